// Round 9
// baseline (379.349 us; speedup 1.0000x reference)
//
#include <hip/hip_runtime.h>

// Problem constants (match reference setup_inputs)
#define BB   512
#define NN   512
#define NNZ  8192
#define EMB  64
#define HID  100
#define DUMPC 512            // dump column for merged-away duplicates (in pad, never read)
#define ASTR 528             // A_d row stride in u16 — EMPIRICALLY low-conflict (r6: 314K vs 520: 4.5M)

// ---------------------------------------------------------------------------
// ws layout (bytes):
//   [0)          csr_rc  int  [B*NNZ]  (row<<16|col)   16,777,216
//   [16777216)   csr_v   bf16 [B*NNZ]                   8,388,608
//   [25165824)   row_st  int  [B*513]                   1,050,624
//   [26216448)   supT    bf16 [B][112][512]            58,720,256
//   [84936704)   w1t     bf16 [112][64]                    14,336
//   [84951040)   w2t     bf16 [112][128]                   28,672
// h1 (bf16 [B][512][112]) lives in d_out; overwritten by final fp32 output.
// ---------------------------------------------------------------------------
#define OFF_CSR_RC  0
#define OFF_CSR_V   16777216
#define OFF_ROWST   25165824
#define OFF_SUPT    26216448
#define OFF_W1T     84936704
#define OFF_W2T     84951040

typedef __attribute__((ext_vector_type(8))) short short8;
typedef __attribute__((ext_vector_type(4))) float floatx4;

__device__ __forceinline__ unsigned short f2bf(float f) {
    unsigned u = __float_as_uint(f);
    unsigned r = (u + 0x7fffu + ((u >> 16) & 1u)) >> 16;
    return (unsigned short)r;
}

__device__ __forceinline__ short8 pack8(float4 a, float4 b) {
    short8 s;
    s[0] = (short)f2bf(a.x); s[1] = (short)f2bf(a.y);
    s[2] = (short)f2bf(a.z); s[3] = (short)f2bf(a.w);
    s[4] = (short)f2bf(b.x); s[5] = (short)f2bf(b.y);
    s[6] = (short)f2bf(b.z); s[7] = (short)f2bf(b.w);
    return s;
}

// ---------------------------------------------------------------------------
// Prep: transposed bf16 weight panels (zero-padded).
// ---------------------------------------------------------------------------
__global__ __launch_bounds__(256) void k_prep(
    const float* __restrict__ W1, const float* __restrict__ W2,
    unsigned short* __restrict__ w1t, unsigned short* __restrict__ w2t)
{
    int id = blockIdx.x * 256 + threadIdx.x;
    if (id < 112 * 64) {
        int h = id >> 6, k = id & 63;
        float f = (h < 100) ? W1[k * 100 + h] : 0.f;
        w1t[id] = f2bf(f);
    }
    if (id < 112 * 128) {
        int h = id >> 7, k = id & 127;
        float f = (h < 100 && k < 100) ? W2[k * 100 + h] : 0.f;
        w2t[id] = f2bf(f);
    }
}

// ---------------------------------------------------------------------------
// CSR build, all-LDS (verified rounds 5-8); csr_v stored bf16.
// ---------------------------------------------------------------------------
__global__ __launch_bounds__(512) void k_csr_build(
    const int* __restrict__ rows, const int* __restrict__ cols,
    const float* __restrict__ vals, int* __restrict__ row_start,
    int* __restrict__ csr_rc, unsigned short* __restrict__ csr_v)
{
    __shared__ int   rl[NNZ];
    __shared__ float vl[NNZ];
    __shared__ int   cnt[NN];
    __shared__ int   sc[NN];

    const int b   = blockIdx.x;
    const int tid = threadIdx.x;       // 0..511 == NN

    const int*   rb = rows + (size_t)b * NNZ;
    const int*   cb = cols + (size_t)b * NNZ;
    const float* vb = vals + (size_t)b * NNZ;

    cnt[tid] = 0;
    __syncthreads();

    #pragma unroll
    for (int i = 0; i < NNZ / 512; ++i)
        atomicAdd(&cnt[rb[tid + i * 512]], 1);
    __syncthreads();

    const int own = cnt[tid];
    sc[tid] = own;
    __syncthreads();
    #pragma unroll
    for (int off = 1; off < NN; off <<= 1) {
        int v = (tid >= off) ? sc[tid - off] : 0;
        __syncthreads();
        sc[tid] += v;
        __syncthreads();
    }
    row_start[b * 513 + tid + 1] = sc[tid];
    if (tid == 0) row_start[b * 513] = 0;
    cnt[tid] = sc[tid] - own;
    __syncthreads();

    #pragma unroll
    for (int i = 0; i < NNZ / 512; ++i) {
        int idx = tid + i * 512;
        int   r = rb[idx];
        int   c = cb[idx];
        float v = vb[idx];
        int pos = atomicAdd(&cnt[r], 1);
        rl[pos] = (r << 16) | c;
        vl[pos] = v;
    }
    __syncthreads();

    // per-row duplicate merge (duplicates redirected to DUMPC)
    {
        const int s = sc[tid] - own;
        const int e = sc[tid];
        for (int j = s; j < e - 1; ++j) {
            int pj = rl[j];
            if ((pj & 0xffff) == DUMPC) continue;
            float add = 0.f;
            bool mod = false;
            for (int j2 = j + 1; j2 < e; ++j2) {
                if (rl[j2] == pj) {
                    add += vl[j2];
                    rl[j2] = (pj & 0xffff0000) | DUMPC;
                    mod = true;
                }
            }
            if (mod) vl[j] += add;
        }
    }
    __syncthreads();

    #pragma unroll
    for (int i = 0; i < NNZ / 512; ++i) {
        int idx = tid + i * 512;
        csr_rc[(size_t)b * NNZ + idx] = rl[idx];
        csr_v [(size_t)b * NNZ + idx] = f2bf(vl[idx]);
    }
}

// ---------------------------------------------------------------------------
// GEMM1 (MFMA): supT[b][col][row] = bf16( emb[hyper] @ W1 ).  (verified r6-r8)
// ---------------------------------------------------------------------------
__global__ __launch_bounds__(256) void k_gemm1_mfma(
    const int* __restrict__ hyper, const float* __restrict__ emb,
    const unsigned short* __restrict__ w1t, unsigned short* __restrict__ supT)
{
    const int lane = threadIdx.x & 63, wave = threadIdx.x >> 6;
    const int l15 = lane & 15, g4 = lane >> 4;

    short8 bq[7][2];
    #pragma unroll
    for (int ct = 0; ct < 7; ++ct)
        #pragma unroll
        for (int kt = 0; kt < 2; ++kt)
            bq[ct][kt] = *(const short8*)(w1t + (ct * 16 + l15) * 64 + kt * 32 + g4 * 8);

    const int wsid = blockIdx.x * 4 + wave;
    #pragma unroll 2
    for (int i = 0; i < 4; ++i) {
        const int  rb   = wsid * 4 + i;
        const long base = (long)rb * 16;
        const int  rid  = hyper[base + l15];
        const float* ep = emb + (long)rid * EMB + g4 * 8;
        float4 f0 = *(const float4*)(ep);
        float4 f1 = *(const float4*)(ep + 4);
        float4 f2 = *(const float4*)(ep + 32);
        float4 f3 = *(const float4*)(ep + 36);
        short8 a0 = pack8(f0, f1);
        short8 a1 = pack8(f2, f3);

        floatx4 acc[7];
        #pragma unroll
        for (int ct = 0; ct < 7; ++ct) acc[ct] = (floatx4)0.f;
        #pragma unroll
        for (int ct = 0; ct < 7; ++ct) {
            acc[ct] = __builtin_amdgcn_mfma_f32_16x16x32_bf16(a0, bq[ct][0], acc[ct], 0, 0, 0);
            acc[ct] = __builtin_amdgcn_mfma_f32_16x16x32_bf16(a1, bq[ct][1], acc[ct], 0, 0, 0);
        }

        const int batch = rb >> 5;
        const int inrow = (rb & 31) * 16 + g4 * 4;
        unsigned short* sp = supT + (size_t)batch * 57344 + inrow;
        #pragma unroll
        for (int ct = 0; ct < 7; ++ct) {
            int col = ct * 16 + l15;
            uint2 w;
            w.x = (unsigned)f2bf(acc[ct][0]) | ((unsigned)f2bf(acc[ct][1]) << 16);
            w.y = (unsigned)f2bf(acc[ct][2]) | ((unsigned)f2bf(acc[ct][3]) << 16);
            *(uint2*)(sp + (size_t)col * 512) = w;
        }
    }
}

// ---------------------------------------------------------------------------
// GEMM2 (MFMA): supT[b][col][row] = bf16( h1 @ W2 ), h1 bf16 [512][112] in
// d_out. k>=112 fragments predicated to zero (replay-safe).  (verified r7/r8)
// ---------------------------------------------------------------------------
__global__ __launch_bounds__(256) void k_gemm2_mfma(
    const unsigned short* __restrict__ h1, const unsigned short* __restrict__ w2t,
    unsigned short* __restrict__ supT)
{
    const int lane = threadIdx.x & 63, wave = threadIdx.x >> 6;
    const int l15 = lane & 15, g4 = lane >> 4;
    const int ct0 = (wave & 1) ? 4 : 0;

    short8 bq[4][4];
    #pragma unroll
    for (int ctl = 0; ctl < 4; ++ctl) {
        int ct = ct0 + ctl;
        if (ct < 7)
            #pragma unroll
            for (int kt = 0; kt < 4; ++kt)
                bq[ctl][kt] = *(const short8*)(w2t + (ct * 16 + l15) * 128 + kt * 32 + g4 * 8);
    }

    const int wp = blockIdx.x * 2 + (wave >> 1);
    #pragma unroll 2
    for (int i = 0; i < 8; ++i) {
        const int  rb   = wp * 8 + i;
        const long base = (long)rb * 16;
        const unsigned short* rp = h1 + (size_t)(base + l15) * 112;

        short8 a[4];
        #pragma unroll
        for (int kt = 0; kt < 4; ++kt) {
            int k0 = kt * 32 + g4 * 8;
            short8 av = (short8)(short)0;
            if (k0 < 112) av = *(const short8*)(rp + k0);
            a[kt] = av;
        }

        floatx4 acc[4];
        #pragma unroll
        for (int ctl = 0; ctl < 4; ++ctl) acc[ctl] = (floatx4)0.f;
        #pragma unroll
        for (int ctl = 0; ctl < 4; ++ctl) {
            if (ct0 + ctl < 7) {
                #pragma unroll
                for (int kt = 0; kt < 4; ++kt)
                    acc[ctl] = __builtin_amdgcn_mfma_f32_16x16x32_bf16(a[kt], bq[ctl][kt], acc[ctl], 0, 0, 0);
            }
        }

        const int batch = rb >> 5;
        const int inrow = (rb & 31) * 16 + g4 * 4;
        unsigned short* sp = supT + (size_t)batch * 57344 + inrow;
        #pragma unroll
        for (int ctl = 0; ctl < 4; ++ctl) {
            if (ct0 + ctl < 7) {
                int col = (ct0 + ctl) * 16 + l15;
                uint2 w;
                w.x = (unsigned)f2bf(acc[ctl][0]) | ((unsigned)f2bf(acc[ctl][1]) << 16);
                w.y = (unsigned)f2bf(acc[ctl][2]) | ((unsigned)f2bf(acc[ctl][3]) << 16);
                *(uint2*)(sp + (size_t)col * 512) = w;
            }
        }
    }
}

// ---------------------------------------------------------------------------
// SpMM + bias via dense-A MFMA. 4096 blocks x 512 threads (8 waves), 64-row
// stripes, ASTR=528, 67.5 KB LDS -> 2 blocks/CU = 16 waves/CU (2x r8's
// latency hiding). Wave (mh, ng): mh = wave>>2 owns rows [mh*32, mh*32+32),
// ng = wave&3 owns n-tiles {2ng, 2ng+1} (ng=3: tile 6 only). B fragments
// double-buffered in registers one kt ahead. XCD-locality swizzle kept
// (FETCH 246 -> 41 MB proven in r8).
// ---------------------------------------------------------------------------
template<bool FINAL>
__global__ __launch_bounds__(512) void k_spmm_mfma(
    const int* __restrict__ row_st, const int* __restrict__ rc,
    const unsigned short* __restrict__ vv, const unsigned short* __restrict__ supT,
    const float* __restrict__ bias, unsigned short* __restrict__ h1,
    float* __restrict__ out)
{
    __shared__ unsigned short Ad[64 * ASTR];     // 67,584 B -> 2 blocks/CU

    const int tid    = threadIdx.x;
    // XCD-locality swizzle (8 XCDs, round-robin blockIdx%8 -> XCD)
    const int xcd    = blockIdx.x & 7;
    const int local  = blockIdx.x >> 3;          // 0..511
    const int batch  = xcd * 64 + (local >> 3);
    const int stripe = local & 7;
    const int r0     = stripe * 64;

    // P1: zero A_d (64*528/8 = 4224 uint4)
    {
        uint4* z = (uint4*)Ad;
        #pragma unroll
        for (int i = 0; i < 9; ++i) {
            int idx = tid + i * 512;
            if (idx < 64 * ASTR / 8) z[idx] = make_uint4(0u, 0u, 0u, 0u);
        }
    }
    __syncthreads();

    // P2: scatter this stripe's entries (dup-free; DUMPC lands in pad)
    const int s0 = row_st[batch * 513 + r0];
    const int e0 = row_st[batch * 513 + r0 + 64];
    const int*            rcb = rc + (size_t)batch * NNZ;
    const unsigned short* vvb = vv + (size_t)batch * NNZ;
    for (int idx = s0 + tid; idx < e0; idx += 512) {
        int p = rcb[idx];
        Ad[((p >> 16) - r0) * ASTR + (p & 0xffff)] = vvb[idx];
    }
    __syncthreads();

    // P3: MFMA — C[64 x 112]; wave (mh, ng)
    const int lane = tid & 63, wave = tid >> 6;
    const int l15 = lane & 15, g4 = lane >> 4;
    const int mh  = wave >> 2;                   // 0,1: row half
    const int ng  = wave & 3;                    // 0..3: n-tile pair
    const int nt0 = ng * 2;
    const bool two = (nt0 + 1) < 7;              // ng=3 owns only n-tile 6

    const unsigned short* b0p = supT + (size_t)batch * 57344 + (nt0 * 16 + l15) * 512 + g4 * 8;
    const unsigned short* b1p = b0p + 16 * 512;
    const unsigned short* ap  = Ad + (mh * 32 + l15) * ASTR + g4 * 8;

    floatx4 acc[2][2];                           // [m][n]
    #pragma unroll
    for (int m = 0; m < 2; ++m)
        #pragma unroll
        for (int n = 0; n < 2; ++n) acc[m][n] = (floatx4)0.f;

    short8 b0 = *(const short8*)(b0p);
    short8 b1 = (short8)(short)0;
    if (two) b1 = *(const short8*)(b1p);

    #pragma unroll
    for (int kt = 0; kt < 16; ++kt) {
        short8 nb0 = b0, nb1 = b1;
        if (kt + 1 < 16) {
            nb0 = *(const short8*)(b0p + (kt + 1) * 32);
            if (two) nb1 = *(const short8*)(b1p + (kt + 1) * 32);
        }
        short8 a0 = *(const short8*)(ap + kt * 32);
        short8 a1 = *(const short8*)(ap + 16 * ASTR + kt * 32);
        acc[0][0] = __builtin_amdgcn_mfma_f32_16x16x32_bf16(a0, b0, acc[0][0], 0, 0, 0);
        acc[1][0] = __builtin_amdgcn_mfma_f32_16x16x32_bf16(a1, b0, acc[1][0], 0, 0, 0);
        if (two) {
            acc[0][1] = __builtin_amdgcn_mfma_f32_16x16x32_bf16(a0, b1, acc[0][1], 0, 0, 0);
            acc[1][1] = __builtin_amdgcn_mfma_f32_16x16x32_bf16(a1, b1, acc[1][1], 0, 0, 0);
        }
        b0 = nb0; b1 = nb1;
    }

    // C write + bias; rows = r0 + mh*32 + m*16 + g4*4 + q, col = nt*16 + l15
    #pragma unroll
    for (int nn = 0; nn < 2; ++nn) {
        int nt = nt0 + nn;
        if (nt >= 7) break;
        int col = nt * 16 + l15;
        if (FINAL) {
            if (col < HID) {
                float bi = bias[col];
                #pragma unroll
                for (int m = 0; m < 2; ++m) {
                    int row = r0 + mh * 32 + m * 16 + g4 * 4;
                    float* op = out + ((size_t)batch * NN + row) * HID + col;
                    #pragma unroll
                    for (int q = 0; q < 4; ++q)
                        op[(size_t)q * HID] = acc[m][nn][q] + bi;
                }
            }
        } else {
            float bi = (col < HID) ? bias[col] : 0.f;  // pad cols: acc==0 -> 0
            #pragma unroll
            for (int m = 0; m < 2; ++m) {
                int row = r0 + mh * 32 + m * 16 + g4 * 4;
                unsigned short* hp = h1 + ((size_t)batch * NN + row) * 112 + col;
                #pragma unroll
                for (int q = 0; q < 4; ++q)
                    hp[(size_t)q * 112] = f2bf(acc[m][nn][q] + bi);
            }
        }
    }
}

// ---------------------------------------------------------------------------
extern "C" void kernel_launch(void* const* d_in, const int* in_sizes, int n_in,
                              void* d_out, int out_size, void* d_ws, size_t ws_size,
                              hipStream_t stream)
{
    const int*   hyper = (const int*)  d_in[0];
    const int*   arows = (const int*)  d_in[1];
    const int*   acols = (const int*)  d_in[2];
    const float* avals = (const float*)d_in[3];
    const float* emb   = (const float*)d_in[4];
    const float* W1    = (const float*)d_in[5];
    const float* b1    = (const float*)d_in[6];
    const float* W2    = (const float*)d_in[7];
    const float* b2    = (const float*)d_in[8];

    float*          out = (float*)d_out;
    unsigned short* h1  = (unsigned short*)d_out;   // bf16 [B][512][112] view
    char*           ws  = (char*)d_ws;

    int*            csr_rc = (int*)           (ws + OFF_CSR_RC);
    unsigned short* csr_v  = (unsigned short*)(ws + OFF_CSR_V);
    int*            row_st = (int*)           (ws + OFF_ROWST);
    unsigned short* supT   = (unsigned short*)(ws + OFF_SUPT);
    unsigned short* w1t    = (unsigned short*)(ws + OFF_W1T);
    unsigned short* w2t    = (unsigned short*)(ws + OFF_W2T);

    // prep transposed bf16 weights
    k_prep<<<56, 256, 0, stream>>>(W1, W2, w1t, w2t);

    // CSR build (all-LDS; A shared by both layers)
    k_csr_build<<<BB, 512, 0, stream>>>(arows, acols, avals, row_st, csr_rc, csr_v);

    // 1) supT = bf16(emb[hyper] @ W1)^T (per batch)
    k_gemm1_mfma<<<1024, 256, 0, stream>>>(hyper, emb, w1t, supT);
    // 2) h1 = bf16(A @ sup1 + b1) -> d_out (bf16 [512][112])
    k_spmm_mfma<false><<<BB * 8, 512, 0, stream>>>(row_st, csr_rc, csr_v, supT, b1, h1, out);
    // 3) supT = bf16(h1 @ W2)^T (per batch)
    k_gemm2_mfma<<<1024, 256, 0, stream>>>(h1, w2t, supT);
    // 4) out = A @ sup2 + b2 -> d_out (fp32)
    k_spmm_mfma<true><<<BB * 8, 512, 0, stream>>>(row_st, csr_rc, csr_v, supT, b2, h1, out);
}

// Round 10
// 299.354 us; speedup vs baseline: 1.2672x; 1.2672x over previous
//
#include <hip/hip_runtime.h>

// Problem constants (match reference setup_inputs)
#define BB   512
#define NN   512
#define NNZ  8192
#define EMB  64
#define HID  100
#define DUMPC 512            // dump column for merged-away duplicates (in pad, never read)
#define ASTR 528             // A_d row stride in u16 — measured low-conflict (r6: 314K vs 520: 4.5M)

// ---------------------------------------------------------------------------
// ws layout (bytes):
//   [0)          csr_rc  int  [B*NNZ]  (row<<16|col)   16,777,216
//   [16777216)   csr_v   bf16 [B*NNZ]                   8,388,608
//   [25165824)   row_st  int  [B*513]                   1,050,624
//   [26216448)   supT    bf16 [B][112][512]            58,720,256
//   [84936704)   w1t     bf16 [112][64]                    14,336
//   [84951040)   w2t     bf16 [112][128]                   28,672
// h1 (bf16 [B][512][112]) lives in d_out; overwritten by final fp32 output.
// ---------------------------------------------------------------------------
#define OFF_CSR_RC  0
#define OFF_CSR_V   16777216
#define OFF_ROWST   25165824
#define OFF_SUPT    26216448
#define OFF_W1T     84936704
#define OFF_W2T     84951040

typedef __attribute__((ext_vector_type(8))) short short8;
typedef __attribute__((ext_vector_type(4))) float floatx4;

__device__ __forceinline__ unsigned short f2bf(float f) {
    unsigned u = __float_as_uint(f);
    unsigned r = (u + 0x7fffu + ((u >> 16) & 1u)) >> 16;
    return (unsigned short)r;
}

__device__ __forceinline__ short8 pack8(float4 a, float4 b) {
    short8 s;
    s[0] = (short)f2bf(a.x); s[1] = (short)f2bf(a.y);
    s[2] = (short)f2bf(a.z); s[3] = (short)f2bf(a.w);
    s[4] = (short)f2bf(b.x); s[5] = (short)f2bf(b.y);
    s[6] = (short)f2bf(b.z); s[7] = (short)f2bf(b.w);
    return s;
}

// ---------------------------------------------------------------------------
// Prep: transposed bf16 weight panels (zero-padded).
// ---------------------------------------------------------------------------
__global__ __launch_bounds__(256) void k_prep(
    const float* __restrict__ W1, const float* __restrict__ W2,
    unsigned short* __restrict__ w1t, unsigned short* __restrict__ w2t)
{
    int id = blockIdx.x * 256 + threadIdx.x;
    if (id < 112 * 64) {
        int h = id >> 6, k = id & 63;
        float f = (h < 100) ? W1[k * 100 + h] : 0.f;
        w1t[id] = f2bf(f);
    }
    if (id < 112 * 128) {
        int h = id >> 7, k = id & 127;
        float f = (h < 100 && k < 100) ? W2[k * 100 + h] : 0.f;
        w2t[id] = f2bf(f);
    }
}

// ---------------------------------------------------------------------------
// CSR build, all-LDS (verified rounds 5-9); csr_v stored bf16.
// ---------------------------------------------------------------------------
__global__ __launch_bounds__(512) void k_csr_build(
    const int* __restrict__ rows, const int* __restrict__ cols,
    const float* __restrict__ vals, int* __restrict__ row_start,
    int* __restrict__ csr_rc, unsigned short* __restrict__ csr_v)
{
    __shared__ int   rl[NNZ];
    __shared__ float vl[NNZ];
    __shared__ int   cnt[NN];
    __shared__ int   sc[NN];

    const int b   = blockIdx.x;
    const int tid = threadIdx.x;       // 0..511 == NN

    const int*   rb = rows + (size_t)b * NNZ;
    const int*   cb = cols + (size_t)b * NNZ;
    const float* vb = vals + (size_t)b * NNZ;

    cnt[tid] = 0;
    __syncthreads();

    #pragma unroll
    for (int i = 0; i < NNZ / 512; ++i)
        atomicAdd(&cnt[rb[tid + i * 512]], 1);
    __syncthreads();

    const int own = cnt[tid];
    sc[tid] = own;
    __syncthreads();
    #pragma unroll
    for (int off = 1; off < NN; off <<= 1) {
        int v = (tid >= off) ? sc[tid - off] : 0;
        __syncthreads();
        sc[tid] += v;
        __syncthreads();
    }
    row_start[b * 513 + tid + 1] = sc[tid];
    if (tid == 0) row_start[b * 513] = 0;
    cnt[tid] = sc[tid] - own;
    __syncthreads();

    #pragma unroll
    for (int i = 0; i < NNZ / 512; ++i) {
        int idx = tid + i * 512;
        int   r = rb[idx];
        int   c = cb[idx];
        float v = vb[idx];
        int pos = atomicAdd(&cnt[r], 1);
        rl[pos] = (r << 16) | c;
        vl[pos] = v;
    }
    __syncthreads();

    // per-row duplicate merge (duplicates redirected to DUMPC)
    {
        const int s = sc[tid] - own;
        const int e = sc[tid];
        for (int j = s; j < e - 1; ++j) {
            int pj = rl[j];
            if ((pj & 0xffff) == DUMPC) continue;
            float add = 0.f;
            bool mod = false;
            for (int j2 = j + 1; j2 < e; ++j2) {
                if (rl[j2] == pj) {
                    add += vl[j2];
                    rl[j2] = (pj & 0xffff0000) | DUMPC;
                    mod = true;
                }
            }
            if (mod) vl[j] += add;
        }
    }
    __syncthreads();

    #pragma unroll
    for (int i = 0; i < NNZ / 512; ++i) {
        int idx = tid + i * 512;
        csr_rc[(size_t)b * NNZ + idx] = rl[idx];
        csr_v [(size_t)b * NNZ + idx] = f2bf(vl[idx]);
    }
}

// ---------------------------------------------------------------------------
// GEMM1 (MFMA): supT[b][col][row] = bf16( emb[hyper] @ W1 ).  (verified r6-r9)
// ---------------------------------------------------------------------------
__global__ __launch_bounds__(256) void k_gemm1_mfma(
    const int* __restrict__ hyper, const float* __restrict__ emb,
    const unsigned short* __restrict__ w1t, unsigned short* __restrict__ supT)
{
    const int lane = threadIdx.x & 63, wave = threadIdx.x >> 6;
    const int l15 = lane & 15, g4 = lane >> 4;

    short8 bq[7][2];
    #pragma unroll
    for (int ct = 0; ct < 7; ++ct)
        #pragma unroll
        for (int kt = 0; kt < 2; ++kt)
            bq[ct][kt] = *(const short8*)(w1t + (ct * 16 + l15) * 64 + kt * 32 + g4 * 8);

    const int wsid = blockIdx.x * 4 + wave;
    #pragma unroll 2
    for (int i = 0; i < 4; ++i) {
        const int  rb   = wsid * 4 + i;
        const long base = (long)rb * 16;
        const int  rid  = hyper[base + l15];
        const float* ep = emb + (long)rid * EMB + g4 * 8;
        float4 f0 = *(const float4*)(ep);
        float4 f1 = *(const float4*)(ep + 4);
        float4 f2 = *(const float4*)(ep + 32);
        float4 f3 = *(const float4*)(ep + 36);
        short8 a0 = pack8(f0, f1);
        short8 a1 = pack8(f2, f3);

        floatx4 acc[7];
        #pragma unroll
        for (int ct = 0; ct < 7; ++ct) acc[ct] = (floatx4)0.f;
        #pragma unroll
        for (int ct = 0; ct < 7; ++ct) {
            acc[ct] = __builtin_amdgcn_mfma_f32_16x16x32_bf16(a0, bq[ct][0], acc[ct], 0, 0, 0);
            acc[ct] = __builtin_amdgcn_mfma_f32_16x16x32_bf16(a1, bq[ct][1], acc[ct], 0, 0, 0);
        }

        const int batch = rb >> 5;
        const int inrow = (rb & 31) * 16 + g4 * 4;
        unsigned short* sp = supT + (size_t)batch * 57344 + inrow;
        #pragma unroll
        for (int ct = 0; ct < 7; ++ct) {
            int col = ct * 16 + l15;
            uint2 w;
            w.x = (unsigned)f2bf(acc[ct][0]) | ((unsigned)f2bf(acc[ct][1]) << 16);
            w.y = (unsigned)f2bf(acc[ct][2]) | ((unsigned)f2bf(acc[ct][3]) << 16);
            *(uint2*)(sp + (size_t)col * 512) = w;
        }
    }
}

// ---------------------------------------------------------------------------
// GEMM2 (MFMA): supT[b][col][row] = bf16( h1 @ W2 ), h1 bf16 [512][112] in
// d_out. k>=112 fragments predicated to zero (replay-safe).  (verified r7-r9)
// ---------------------------------------------------------------------------
__global__ __launch_bounds__(256) void k_gemm2_mfma(
    const unsigned short* __restrict__ h1, const unsigned short* __restrict__ w2t,
    unsigned short* __restrict__ supT)
{
    const int lane = threadIdx.x & 63, wave = threadIdx.x >> 6;
    const int l15 = lane & 15, g4 = lane >> 4;
    const int ct0 = (wave & 1) ? 4 : 0;

    short8 bq[4][4];
    #pragma unroll
    for (int ctl = 0; ctl < 4; ++ctl) {
        int ct = ct0 + ctl;
        if (ct < 7)
            #pragma unroll
            for (int kt = 0; kt < 4; ++kt)
                bq[ctl][kt] = *(const short8*)(w2t + (ct * 16 + l15) * 128 + kt * 32 + g4 * 8);
    }

    const int wp = blockIdx.x * 2 + (wave >> 1);
    #pragma unroll 2
    for (int i = 0; i < 8; ++i) {
        const int  rb   = wp * 8 + i;
        const long base = (long)rb * 16;
        const unsigned short* rp = h1 + (size_t)(base + l15) * 112;

        short8 a[4];
        #pragma unroll
        for (int kt = 0; kt < 4; ++kt) {
            int k0 = kt * 32 + g4 * 8;
            short8 av = (short8)(short)0;
            if (k0 < 112) av = *(const short8*)(rp + k0);
            a[kt] = av;
        }

        floatx4 acc[4];
        #pragma unroll
        for (int ctl = 0; ctl < 4; ++ctl) acc[ctl] = (floatx4)0.f;
        #pragma unroll
        for (int ctl = 0; ctl < 4; ++ctl) {
            if (ct0 + ctl < 7) {
                #pragma unroll
                for (int kt = 0; kt < 4; ++kt)
                    acc[ctl] = __builtin_amdgcn_mfma_f32_16x16x32_bf16(a[kt], bq[ctl][kt], acc[ctl], 0, 0, 0);
            }
        }

        const int batch = rb >> 5;
        const int inrow = (rb & 31) * 16 + g4 * 4;
        unsigned short* sp = supT + (size_t)batch * 57344 + inrow;
        #pragma unroll
        for (int ctl = 0; ctl < 4; ++ctl) {
            if (ct0 + ctl < 7) {
                int col = (ct0 + ctl) * 16 + l15;
                uint2 w;
                w.x = (unsigned)f2bf(acc[ctl][0]) | ((unsigned)f2bf(acc[ctl][1]) << 16);
                w.y = (unsigned)f2bf(acc[ctl][2]) | ((unsigned)f2bf(acc[ctl][3]) << 16);
                *(uint2*)(sp + (size_t)col * 512) = w;
            }
        }
    }
}

// ---------------------------------------------------------------------------
// SpMM + bias via dense-A MFMA. r8 geometry (4096 x 256-thr blocks, 64-row
// stripes, 2 blocks/CU, XCD swizzle — FETCH 41MB proven) + 3 fixes:
//  (1) ASTR 528 (bank conflicts 4.5M -> ~300K, r6-measured),
//  (2) issue-early scatter: CSR entries loaded to regs BEFORE zeroing,
//      ds_write after barrier (HBM latency hidden under zero phase),
//  (3) C staged through dead A_d LDS -> fully coalesced 16B global stores.
// ---------------------------------------------------------------------------
template<bool FINAL>
__global__ __launch_bounds__(256) void k_spmm_mfma(
    const int* __restrict__ row_st, const int* __restrict__ rc,
    const unsigned short* __restrict__ vv, const unsigned short* __restrict__ supT,
    const float* __restrict__ bias, unsigned short* __restrict__ h1,
    float* __restrict__ out)
{
    __shared__ unsigned short Ad[64 * ASTR];     // 67,584 B -> 2 blocks/CU

    const int tid    = threadIdx.x;
    // XCD-locality swizzle (8 XCDs, round-robin blockIdx%8 -> XCD)
    const int xcd    = blockIdx.x & 7;
    const int local  = blockIdx.x >> 3;          // 0..511
    const int batch  = xcd * 64 + (local >> 3);
    const int stripe = local & 7;
    const int r0     = stripe * 64;

    // P0: issue CSR loads EARLY (use-late after the zero phase)
    const int s0 = row_st[batch * 513 + r0];
    const int e0 = row_st[batch * 513 + r0 + 64];
    const int*            rcb = rc + (size_t)batch * NNZ;
    const unsigned short* vvb = vv + (size_t)batch * NNZ;
    int            pc[5];
    unsigned short pv[5];
    #pragma unroll
    for (int i = 0; i < 5; ++i) {
        int idx = s0 + tid + i * 256;
        bool ok = idx < e0;
        pc[i] = ok ? rcb[idx] : 0;
        pv[i] = ok ? vvb[idx] : 0;
    }

    // P1: zero A_d (64*528/8 = 4224 uint4)
    {
        uint4* z = (uint4*)Ad;
        #pragma unroll
        for (int i = 0; i < 17; ++i) {
            int idx = tid + i * 256;
            if (idx < 64 * ASTR / 8) z[idx] = make_uint4(0u, 0u, 0u, 0u);
        }
    }
    __syncthreads();

    // P2: scatter from regs (dup-free; DUMPC lands in pad)
    #pragma unroll
    for (int i = 0; i < 5; ++i) {
        int idx = s0 + tid + i * 256;
        if (idx < e0)
            Ad[((pc[i] >> 16) - r0) * ASTR + (pc[i] & 0xffff)] = pv[i];
    }
    // overflow fallback (cnt > 1280: statistically never, correctness only)
    for (int idx = s0 + 1280 + tid; idx < e0; idx += 256) {
        int p = rcb[idx];
        Ad[((p >> 16) - r0) * ASTR + (p & 0xffff)] = vvb[idx];
    }
    __syncthreads();

    // P3: MFMA — C[64 x 112]; wave owns n-tiles {2w, 2w+1}, all 4 m-tiles
    const int lane = tid & 63, wave = tid >> 6;
    const int l15 = lane & 15, g4 = lane >> 4;
    const int nt0 = wave * 2;
    const bool two = (nt0 + 1) < 7;              // wave3 owns only n-tile 6

    const unsigned short* b0p = supT + (size_t)batch * 57344 + (nt0 * 16 + l15) * 512 + g4 * 8;
    const unsigned short* b1p = b0p + 16 * 512;
    const unsigned short* ap  = Ad + l15 * ASTR + g4 * 8;

    floatx4 acc[2][4];
    #pragma unroll
    for (int n = 0; n < 2; ++n)
        #pragma unroll
        for (int m = 0; m < 4; ++m) acc[n][m] = (floatx4)0.f;

    #pragma unroll 4
    for (int kt = 0; kt < 16; ++kt) {
        short8 b0 = *(const short8*)(b0p + kt * 32);
        short8 b1 = (short8)(short)0;
        if (two) b1 = *(const short8*)(b1p + kt * 32);
        #pragma unroll
        for (int m = 0; m < 4; ++m) {
            short8 a = *(const short8*)(ap + m * 16 * ASTR + kt * 32);
            acc[0][m] = __builtin_amdgcn_mfma_f32_16x16x32_bf16(a, b0, acc[0][m], 0, 0, 0);
            if (two)
                acc[1][m] = __builtin_amdgcn_mfma_f32_16x16x32_bf16(a, b1, acc[1][m], 0, 0, 0);
        }
    }
    __syncthreads();   // A_d dead; reuse as C staging buffer

    // P4: stage C into LDS (+bias), then coalesced writeback
    if (FINAL) {
        float* st = (float*)Ad;                  // [64][112] f32 = 28.7 KB
        #pragma unroll
        for (int nn = 0; nn < 2; ++nn) {
            int nt = nt0 + nn;
            if (nt >= 7) break;
            int col = nt * 16 + l15;
            float bi = (col < HID) ? bias[col] : 0.f;
            #pragma unroll
            for (int m = 0; m < 4; ++m) {
                int row = m * 16 + g4 * 4;
                #pragma unroll
                for (int q = 0; q < 4; ++q)
                    st[(row + q) * 112 + col] = acc[nn][m][q] + bi;
            }
        }
        __syncthreads();
        // copy out [64][100] f32: 64*25 = 1600 float4 rows-major
        #pragma unroll
        for (int i = 0; i < 7; ++i) {
            int flat = tid + i * 256;
            if (flat < 1600) {
                int row = flat / 25, wi = flat - row * 25;
                float4 v = *(const float4*)(st + row * 112 + wi * 4);
                *(float4*)(out + ((size_t)batch * NN + r0 + row) * HID + wi * 4) = v;
            }
        }
    } else {
        unsigned short* st = Ad;                 // [64][112] bf16 = 14 KB
        #pragma unroll
        for (int nn = 0; nn < 2; ++nn) {
            int nt = nt0 + nn;
            if (nt >= 7) break;
            int col = nt * 16 + l15;
            float bi = (col < HID) ? bias[col] : 0.f;   // pad cols: acc==0 -> 0
            #pragma unroll
            for (int m = 0; m < 4; ++m) {
                int row = m * 16 + g4 * 4;
                #pragma unroll
                for (int q = 0; q < 4; ++q)
                    st[(row + q) * 112 + col] = f2bf(acc[nn][m][q] + bi);
            }
        }
        __syncthreads();
        // copy out [64][112] bf16: 896 uint4
        #pragma unroll
        for (int i = 0; i < 4; ++i) {
            int flat = tid + i * 256;
            if (flat < 896) {
                int row = flat / 14, wi = flat - row * 14;
                uint4 v = *(const uint4*)(st + row * 112 + wi * 8);
                *(uint4*)(h1 + ((size_t)batch * NN + r0 + row) * 112 + wi * 8) = v;
            }
        }
    }
}

// ---------------------------------------------------------------------------
extern "C" void kernel_launch(void* const* d_in, const int* in_sizes, int n_in,
                              void* d_out, int out_size, void* d_ws, size_t ws_size,
                              hipStream_t stream)
{
    const int*   hyper = (const int*)  d_in[0];
    const int*   arows = (const int*)  d_in[1];
    const int*   acols = (const int*)  d_in[2];
    const float* avals = (const float*)d_in[3];
    const float* emb   = (const float*)d_in[4];
    const float* W1    = (const float*)d_in[5];
    const float* b1    = (const float*)d_in[6];
    const float* W2    = (const float*)d_in[7];
    const float* b2    = (const float*)d_in[8];

    float*          out = (float*)d_out;
    unsigned short* h1  = (unsigned short*)d_out;   // bf16 [B][512][112] view
    char*           ws  = (char*)d_ws;

    int*            csr_rc = (int*)           (ws + OFF_CSR_RC);
    unsigned short* csr_v  = (unsigned short*)(ws + OFF_CSR_V);
    int*            row_st = (int*)           (ws + OFF_ROWST);
    unsigned short* supT   = (unsigned short*)(ws + OFF_SUPT);
    unsigned short* w1t    = (unsigned short*)(ws + OFF_W1T);
    unsigned short* w2t    = (unsigned short*)(ws + OFF_W2T);

    // prep transposed bf16 weights
    k_prep<<<56, 256, 0, stream>>>(W1, W2, w1t, w2t);

    // CSR build (all-LDS; A shared by both layers)
    k_csr_build<<<BB, 512, 0, stream>>>(arows, acols, avals, row_st, csr_rc, csr_v);

    // 1) supT = bf16(emb[hyper] @ W1)^T (per batch)
    k_gemm1_mfma<<<1024, 256, 0, stream>>>(hyper, emb, w1t, supT);
    // 2) h1 = bf16(A @ sup1 + b1) -> d_out (bf16 [512][112])
    k_spmm_mfma<false><<<BB * 8, 256, 0, stream>>>(row_st, csr_rc, csr_v, supT, b1, h1, out);
    // 3) supT = bf16(h1 @ W2)^T (per batch)
    k_gemm2_mfma<<<1024, 256, 0, stream>>>(h1, w2t, supT);
    // 4) out = A @ sup2 + b2 -> d_out (fp32)
    k_spmm_mfma<true><<<BB * 8, 256, 0, stream>>>(row_st, csr_rc, csr_v, supT, b2, h1, out);
}